// Round 7
// baseline (242.363 us; speedup 1.0000x reference)
//
#include <hip/hip_runtime.h>
#include <hip/hip_bf16.h>
#include <math.h>

// Problem constants (B=16, T=3000, F=201)
constexpr int BB     = 16;
constexpr int T      = 3000;
constexpr int F      = 201;
constexpr int NFFT   = 400;
constexpr int HOP    = 160;
constexpr int K      = 402;            // 2*F real/imag interleaved
constexpr int ESTLEN = (T - 1) * HOP + NFFT;   // 480240
constexpr int OUTLEN = ESTLEN - NFFT;          // 479840 per batch
constexpr float EPS  = 1e-12f;

constexpr int WJ    = 416;             // W rows per step (j 0..415; >=400 zero)
constexpr int WSTEP = WJ * 32;         // shorts per k32 table step = 13312 (26624 B)
constexpr int NSTEP = 13;              // k-steps of 32 (step 12 = tail 384..401)
constexpr int UT    = 96;              // u-rows per block (3 wu x 32)
constexpr int ARR   = 98;              // A rows per tile (halo 2)
constexpr int NTHR  = 384;             // 6 waves: (kh 0..1) x (wu 0..2)

typedef short bf16x8 __attribute__((ext_vector_type(8)));
typedef float f32x16 __attribute__((ext_vector_type(16)));

__device__ __forceinline__ unsigned short f2bf(float f) {
    unsigned int u = __float_as_uint(f);
    u = (u + 0x7fffu + ((u >> 16) & 1u)) >> 16;
    return (unsigned short)u;
}

// ---------------- table builders ----------------
// Baked bank-swizzle: Wg[ksg][j][op][i] = W[k = ksg*32 + (op ^ ((j>>1)&3))*8 + i][j]
__global__ void build_wt(unsigned short* __restrict__ Wg) {
    int idx = blockIdx.x * blockDim.x + threadIdx.x;
    if (idx >= NSTEP * WSTEP) return;
    int ksg = idx / WSTEP;
    int rem = idx - ksg * WSTEP;
    int j  = rem >> 5;
    int kk = rem & 31;
    int op = kk >> 3;
    int i  = kk & 7;
    int ol = op ^ ((j >> 1) & 3);
    int k  = ksg * 32 + ol * 8 + i;
    float v = 0.f;
    if (j < NFFT && k < K) {
        int f = k >> 1;
        bool is_re = (k & 1) == 0;
        float c = (f == 0 || f == F - 1) ? (1.f / 400.f) : (2.f / 400.f);
        int m = (j * f) % NFFT;
        float ang = (float)(2.0 * M_PI * (double)m / 400.0);
        float tw = is_re ? cosf(ang) : -sinf(ang);
        float win = 0.54f - 0.46f * cosf((float)(2.0 * M_PI * (double)j / 400.0));
        v = c * tw * win;
    }
    Wg[idx] = f2bf(v);
}

__global__ void build_rssw(float* __restrict__ rssw) {
    int p = blockIdx.x * blockDim.x + threadIdx.x;
    if (p >= ESTLEN) return;
    int t_hi = p / HOP; if (t_hi > T - 1) t_hi = T - 1;
    int t_lo = (p >= NFFT) ? ((p - NFFT) / HOP + 1) : 0;
    float s = 0.f;
    for (int t = t_lo; t <= t_hi; ++t) {
        int j = p - t * HOP;
        float w = 0.54f - 0.46f * cosf((float)(2.0 * M_PI * (double)j / 400.0));
        s += w * w;
    }
    rssw[p] = (s > EPS) ? 1.f / s : 1.f;
}

// ---------------- fused MFMA gather-GEMM (ablation template) ----------------
// V0 FULL | V1 no-W-stage | V2 no-A-stage | V3 compute-only,no-bar | V4 stage-only
template<int V>
__global__ __launch_bounds__(NTHR, 3)
void istft_fused(const float* __restrict__ A, const unsigned short* __restrict__ Wg,
                 const float* __restrict__ rssw, const float* __restrict__ zpage,
                 float* __restrict__ out) {
    constexpr bool DO_W    = (V == 0) || (V == 2) || (V == 4);
    constexpr bool DO_A    = (V == 0) || (V == 1) || (V == 4);
    constexpr bool DO_MFMA = (V != 4);
    constexpr bool DO_BAR  = (V != 3);

    __shared__ __align__(16) unsigned short smem[2 * WSTEP + 2 * ARR * 32]; // 65792 B
    unsigned short* WsBuf = smem;
    unsigned short* AsBuf = smem + 2 * WSTEP;

    const int tid  = threadIdx.x;
    const int lane = tid & 63;
    const int w    = tid >> 6;
    const int kh   = (w >= 3) ? 1 : 0;
    const int wu   = kh ? (w - 3) : w;     // 0..2
    const int lj   = lane & 31;
    const int lh   = lane >> 5;
    const int b    = blockIdx.y;
    const int u0   = 1 + blockIdx.x * UT;
    const int tbase = u0 - 2;

    f32x16 acc[5];
    #pragma unroll
    for (int mf = 0; mf < 5; ++mf)
        #pragma unroll
        for (int q = 0; q < 16; ++q) acc[mf][q] = 0.f;

    // ---- A staging maps ----
    const int r0  = tid >> 2, p0 = tid & 3;
    const int cl0 = p0 ^ ((r0 >> 1) & 3);
    const int t0  = tbase + r0;
    const float* arow0 = (t0 >= 0 && t0 < T) ? A + (size_t)(b * T + t0) * K : zpage;
    const bool has2 = (tid < 8);
    const int r1  = 96 + (tid >> 2), p1 = tid & 3;
    const int cl1 = p1 ^ ((r1 >> 1) & 3);
    const int t1  = tbase + r1;
    const float* arow1 = (t1 >= 0 && t1 < T) ? A + (size_t)(b * T + t1) * K : zpage;

    auto loadA = [&](int k0, bool tail, float4* d) {
        if (!tail) {
            const float* s0 = arow0 + k0 + cl0 * 8;
            d[0] = *reinterpret_cast<const float4*>(s0);
            d[1] = *reinterpret_cast<const float4*>(s0 + 4);
            if (has2) {
                const float* s1 = arow1 + k0 + cl1 * 8;
                d[2] = *reinterpret_cast<const float4*>(s1);
                d[3] = *reinterpret_cast<const float4*>(s1 + 4);
            }
        } else {
            float v0[8], v1[8];
            #pragma unroll
            for (int i = 0; i < 8; ++i) {
                int ka = k0 + cl0 * 8 + i;
                v0[i] = (ka < K) ? arow0[ka] : 0.f;
            }
            d[0] = make_float4(v0[0], v0[1], v0[2], v0[3]);
            d[1] = make_float4(v0[4], v0[5], v0[6], v0[7]);
            if (has2) {
                #pragma unroll
                for (int i = 0; i < 8; ++i) {
                    int ka = k0 + cl1 * 8 + i;
                    v1[i] = (ka < K) ? arow1[ka] : 0.f;
                }
                d[2] = make_float4(v1[0], v1[1], v1[2], v1[3]);
                d[3] = make_float4(v1[4], v1[5], v1[6], v1[7]);
            }
        }
    };

    auto writeA = [&](unsigned short* dst, const float4* d) {
        union { bf16x8 v; __hip_bfloat162 h[4]; } u;
        u.h[0] = __float22bfloat162_rn(make_float2(d[0].x, d[0].y));
        u.h[1] = __float22bfloat162_rn(make_float2(d[0].z, d[0].w));
        u.h[2] = __float22bfloat162_rn(make_float2(d[1].x, d[1].y));
        u.h[3] = __float22bfloat162_rn(make_float2(d[1].z, d[1].w));
        *reinterpret_cast<bf16x8*>(&dst[r0 * 32 + p0 * 8]) = u.v;
        if (has2) {
            union { bf16x8 v; __hip_bfloat162 h[4]; } u2;
            u2.h[0] = __float22bfloat162_rn(make_float2(d[2].x, d[2].y));
            u2.h[1] = __float22bfloat162_rn(make_float2(d[2].z, d[2].w));
            u2.h[2] = __float22bfloat162_rn(make_float2(d[3].x, d[3].y));
            u2.h[3] = __float22bfloat162_rn(make_float2(d[3].z, d[3].w));
            *reinterpret_cast<bf16x8*>(&dst[r1 * 32 + p1 * 8]) = u2.v;
        }
    };

    auto issueW = [&](unsigned short* dst, int ksg) {
        const unsigned short* sb = Wg + (size_t)ksg * WSTEP;
        #pragma unroll
        for (int p = 0; p < 5; ++p) {
            int P = p * NTHR + tid;
            if (P < WJ * 4) {
                __builtin_amdgcn_global_load_lds(
                    (const __attribute__((address_space(1))) void*)(sb + (size_t)P * 8),
                    (__attribute__((address_space(3))) void*)(dst + (p * NTHR + w * 64) * 8),
                    16, 0, 0);
            }
        }
    };

    const int q4  = kh * 2 + lh;
    const int spl = q4 ^ ((lj >> 1) & 3);

    auto compute = [&](int buf) {
        const unsigned short* Wb = WsBuf + buf * WSTEP;
        const unsigned short* Ab = AsBuf + buf * (ARR * 32);
        bf16x8 af[3];
        #pragma unroll
        for (int dt = 0; dt < 3; ++dt) {
            int r  = wu * 32 + lj + 2 - dt;
            int sl = q4 ^ ((r >> 1) & 3);
            af[dt] = *reinterpret_cast<const bf16x8*>(&Ab[r * 32 + sl * 8]);
        }
        #pragma unroll
        for (int dt = 0; dt < 3; ++dt) {
            const int nmf = (dt < 2) ? 5 : 3;
            #pragma unroll
            for (int mf = 0; mf < 5; ++mf) {
                if (mf < nmf) {
                    int j = dt * 160 + mf * 32 + lj;
                    bf16x8 bf = *reinterpret_cast<const bf16x8*>(&Wb[j * 32 + spl * 8]);
                    acc[mf] = __builtin_amdgcn_mfma_f32_32x32x16_bf16(
                        af[dt], bf, acc[mf], 0, 0, 0);
                }
            }
        }
    };

    // ---- prologue: stage step 0 ----
    {
        if constexpr (DO_A) {
            float4 d[4];
            loadA(0, false, d);
            if constexpr (DO_W) issueW(WsBuf, 0);
            writeA(AsBuf, d);
        } else if constexpr (DO_W) {
            issueW(WsBuf, 0);
        }
        __syncthreads();
    }

    // ---- main loop ----
    for (int s = 0; s < NSTEP; ++s) {
        const int cur = s & 1, nxt = cur ^ 1;
        const bool dn = (s + 1 < NSTEP);
        float4 d[4];
        if (dn) {
            if constexpr (DO_A) loadA((s + 1) * 32, (s + 1) == 12, d);
            if constexpr (DO_W) issueW(WsBuf + nxt * WSTEP, s + 1);
        }
        if constexpr (DO_MFMA) compute(cur);
        if (dn) {
            if constexpr (DO_A) writeA(AsBuf + nxt * (ARR * 32), d);
        }
        if constexpr (DO_BAR) __syncthreads();
        else asm volatile("" ::: "memory");   // keep per-iter LDS reads honest, no sync
    }

    // ---- kh reduction via LDS + normalized stores (identical in all variants) ----
    float* xch = reinterpret_cast<float*>(smem);
    __syncthreads();
    if (kh == 1) {
        #pragma unroll
        for (int mf = 0; mf < 5; ++mf) {
            int base = ((wu * 5 + mf) * 64 + lane) * 16;
            #pragma unroll
            for (int q = 0; q < 4; ++q)
                *reinterpret_cast<float4*>(&xch[base + q * 4]) =
                    make_float4(acc[mf][q * 4], acc[mf][q * 4 + 1],
                                acc[mf][q * 4 + 2], acc[mf][q * 4 + 3]);
        }
    }
    __syncthreads();
    if (kh == 0) {
        #pragma unroll
        for (int mf = 0; mf < 5; ++mf) {
            int base = ((wu * 5 + mf) * 64 + lane) * 16;
            float part[16];
            #pragma unroll
            for (int q = 0; q < 4; ++q) {
                float4 v = *reinterpret_cast<const float4*>(&xch[base + q * 4]);
                part[q * 4] = v.x; part[q * 4 + 1] = v.y;
                part[q * 4 + 2] = v.z; part[q * 4 + 3] = v.w;
            }
            int m = mf * 32 + lj;
            #pragma unroll
            for (int rg = 0; rg < 16; ++rg) {
                int u  = u0 + wu * 32 + (rg & 3) + 8 * (rg >> 2) + 4 * lh;
                int pe = u * HOP + m;
                int po = pe - (NFFT / 2);
                if (po >= 0 && po < OUTLEN)
                    out[(size_t)b * OUTLEN + po] = (acc[mf][rg] + part[rg]) * rssw[pe];
            }
        }
    }
}

// ---------------- launcher ----------------
extern "C" void kernel_launch(void* const* d_in, const int* in_sizes, int n_in,
                              void* d_out, int out_size, void* d_ws, size_t ws_size,
                              hipStream_t stream) {
    const float* x = (const float*)d_in[0];
    float* out = (float*)d_out;

    char* ws = (char*)d_ws;
    unsigned short* Wg = (unsigned short*)ws;                    // 346,112 B
    float* rssw = (float*)(ws + 346112);                         // 1,920,960 B
    float* zpage = (float*)(ws + 346112 + 1920960);              // 2048 B zeros

    hipMemsetAsync(zpage, 0, 2048, stream);
    {
        int total = NSTEP * WSTEP;
        build_wt<<<(total + 255) / 256, 256, 0, stream>>>(Wg);
    }
    {
        build_rssw<<<(ESTLEN + 255) / 256, 256, 0, stream>>>(rssw);
    }
    dim3 grid((T + UT - 1) / UT, BB);                            // 32 x 16 = 512

    // Ablation dispatches (write garbage to d_out; overwritten by V0 below).
    istft_fused<4><<<grid, NTHR, 0, stream>>>(x, Wg, rssw, zpage, out); // stage-only
    istft_fused<3><<<grid, NTHR, 0, stream>>>(x, Wg, rssw, zpage, out); // compute-only
    istft_fused<2><<<grid, NTHR, 0, stream>>>(x, Wg, rssw, zpage, out); // no-A-stage
    istft_fused<1><<<grid, NTHR, 0, stream>>>(x, Wg, rssw, zpage, out); // no-W-stage
    // FULL (correct output) — must be last.
    istft_fused<0><<<grid, NTHR, 0, stream>>>(x, Wg, rssw, zpage, out);
}

// Round 8
// 95.819 us; speedup vs baseline: 2.5294x; 2.5294x over previous
//
#include <hip/hip_runtime.h>
#include <hip/hip_bf16.h>
#include <math.h>

// Problem constants (B=16, T=3000, F=201)
constexpr int BB     = 16;
constexpr int T      = 3000;
constexpr int F      = 201;
constexpr int NFFT   = 400;
constexpr int HOP    = 160;
constexpr int K      = 402;            // 2*F real/imag interleaved
constexpr int ESTLEN = (T - 1) * HOP + NFFT;   // 480240
constexpr int OUTLEN = ESTLEN - NFFT;          // 479840 per batch
constexpr float EPS  = 1e-12f;

constexpr int WJ    = 416;             // W rows per step (j 0..415; >=400 zero)
constexpr int WSTEP = WJ * 32;         // shorts per W LDS buffer = 13312 (26624 B)
constexpr int NSTEP = 13;              // k-steps of 32 (step 12 = tail 384..401)
constexpr int UT    = 96;              // u-rows per block (3 wu x 32)
constexpr int ARR   = 98;              // A rows per tile (halo 2)
constexpr int NTHR  = 384;             // 6 waves: (kh 0..1) x (wu 0..2)

typedef short bf16x8 __attribute__((ext_vector_type(8)));
typedef float f32x16 __attribute__((ext_vector_type(16)));

constexpr float TWO_PI = 6.28318530717958647692f;

// reciprocal sum-of-squared-window table
__global__ void build_rssw(float* __restrict__ rssw) {
    int p = blockIdx.x * blockDim.x + threadIdx.x;
    if (p >= ESTLEN) return;
    int t_hi = p / HOP; if (t_hi > T - 1) t_hi = T - 1;
    int t_lo = (p >= NFFT) ? ((p - NFFT) / HOP + 1) : 0;
    float s = 0.f;
    for (int t = t_lo; t <= t_hi; ++t) {
        int j = p - t * HOP;
        float w = 0.54f - 0.46f * cosf((float)(2.0 * M_PI * (double)j / 400.0));
        s += w * w;
    }
    rssw[p] = (s > EPS) ? 1.f / s : 1.f;
}

// ---------------- fused MFMA gather-GEMM, W generated in-VALU ----------------
// Block 384 thr = 6 waves: (kh 0..1) x (wu 0..2). Tile 96u x 160m.
// Wave: 32u x 160m, k-half kh. 32x32x16 MFMA. K: 13 steps of 32 (step12 tail).
// W LDS layout (as r6): [j][op][i] shorts, where stored (j,op) holds
// k = s*32 + (op ^ ((j>>1)&3))*8 + i  -> compute reads op = q4 ^ ((lj>>1)&3).
__global__ __launch_bounds__(NTHR, 3)
void istft_fused(const float* __restrict__ A, const float* __restrict__ rssw,
                 const float* __restrict__ zpage, float* __restrict__ out) {
    __shared__ __align__(16) unsigned short smem[2 * WSTEP + 2 * ARR * 32]; // 65792 B
    unsigned short* WsBuf = smem;
    unsigned short* AsBuf = smem + 2 * WSTEP;

    const int tid  = threadIdx.x;
    const int lane = tid & 63;
    const int w    = tid >> 6;
    const int kh   = (w >= 3) ? 1 : 0;
    const int wu   = kh ? (w - 3) : w;     // 0..2
    const int lj   = lane & 31;
    const int lh   = lane >> 5;
    const int b    = blockIdx.y;
    const int u0   = 1 + blockIdx.x * UT;
    const int tbase = u0 - 2;

    f32x16 acc[5];
    #pragma unroll
    for (int mf = 0; mf < 5; ++mf)
        #pragma unroll
        for (int q = 0; q < 16; ++q) acc[mf][q] = 0.f;

    // ---- per-thread W-gen item constants (5 items, loop-invariant) ----
    // item: P = it*NTHR + tid (valid if P < WJ*4); j = P>>2, op = P&3,
    // ol = op ^ ((j>>1)&3); f-base at step s = s*16 + ol*4.
    float item_jf[5], item_w[5], item_fb[5];
    int   item_off[5];
    #pragma unroll
    for (int it = 0; it < 5; ++it) {
        int P  = it * NTHR + tid;
        int Pc = (P < WJ * 4) ? P : 0;
        int j  = Pc >> 2;
        int op = Pc & 3;
        int ol = op ^ ((j >> 1) & 3);
        item_jf[it] = (float)j;
        float win = 0.54f - 0.46f * __cosf((float)j * (TWO_PI / 400.0f));
        item_w[it] = (j < NFFT) ? win * 0.005f : 0.0f;   // 2/400 baked
        item_fb[it] = (float)(ol * 4);
        item_off[it] = Pc * 8;                            // shorts (16B/item)
    }

    // genW: fill dst with step-s W slice. Linear ds_write_b128 per item.
    auto genW = [&](unsigned short* dst, int s) {
        const float fs = (float)(s * 16);
        #pragma unroll
        for (int it = 0; it < 5; ++it) {
            if (it < 4 || tid < (WJ * 4 - 4 * NTHR)) {    // it=4: tid < 128
                float fb = fs + item_fb[it];
                float jf = item_jf[it];
                float wj = item_w[it];
                union { bf16x8 v; __hip_bfloat162 h[4]; } u;
                #pragma unroll
                for (int q = 0; q < 4; ++q) {
                    float fi = fb + (float)q;
                    float sc = wj;
                    if (s == 0)  { if (fi == 0.0f) sc *= 0.5f; }
                    if (s == 12) { sc = (fi > 200.0f) ? 0.0f
                                      : ((fi == 200.0f) ? sc * 0.5f : sc); }
                    float rv  = jf * fi * (1.0f / 400.0f);
                    float rev = rv - floorf(rv);
                    float ang = rev * TWO_PI;
                    float cv  =  __cosf(ang) * sc;
                    float sv  = -__sinf(ang) * sc;
                    u.h[q] = __float22bfloat162_rn(make_float2(cv, sv));
                }
                *reinterpret_cast<bf16x8*>(&dst[item_off[it]]) = u.v;
            }
        }
    };

    // ---- A staging maps (coalesced: 4 threads/row x 32B; reg-staged) ----
    const int r0  = tid >> 2, p0 = tid & 3;
    const int cl0 = p0 ^ ((r0 >> 1) & 3);
    const int t0  = tbase + r0;
    const float* arow0 = (t0 >= 0 && t0 < T) ? A + (size_t)(b * T + t0) * K : zpage;
    const bool has2 = (tid < 8);
    const int r1  = 96 + (tid >> 2), p1 = tid & 3;
    const int cl1 = p1 ^ ((r1 >> 1) & 3);
    const int t1  = tbase + r1;
    const float* arow1 = (t1 >= 0 && t1 < T) ? A + (size_t)(b * T + t1) * K : zpage;

    auto loadA = [&](int k0, bool tail, float4* d) {
        if (!tail) {
            const float* s0 = arow0 + k0 + cl0 * 8;
            d[0] = *reinterpret_cast<const float4*>(s0);
            d[1] = *reinterpret_cast<const float4*>(s0 + 4);
            if (has2) {
                const float* s1 = arow1 + k0 + cl1 * 8;
                d[2] = *reinterpret_cast<const float4*>(s1);
                d[3] = *reinterpret_cast<const float4*>(s1 + 4);
            }
        } else {
            float v0[8], v1[8];
            #pragma unroll
            for (int i = 0; i < 8; ++i) {
                int ka = k0 + cl0 * 8 + i;
                v0[i] = (ka < K) ? arow0[ka] : 0.f;
            }
            d[0] = make_float4(v0[0], v0[1], v0[2], v0[3]);
            d[1] = make_float4(v0[4], v0[5], v0[6], v0[7]);
            if (has2) {
                #pragma unroll
                for (int i = 0; i < 8; ++i) {
                    int ka = k0 + cl1 * 8 + i;
                    v1[i] = (ka < K) ? arow1[ka] : 0.f;
                }
                d[2] = make_float4(v1[0], v1[1], v1[2], v1[3]);
                d[3] = make_float4(v1[4], v1[5], v1[6], v1[7]);
            }
        }
    };

    auto writeA = [&](unsigned short* dst, const float4* d) {
        union { bf16x8 v; __hip_bfloat162 h[4]; } u;
        u.h[0] = __float22bfloat162_rn(make_float2(d[0].x, d[0].y));
        u.h[1] = __float22bfloat162_rn(make_float2(d[0].z, d[0].w));
        u.h[2] = __float22bfloat162_rn(make_float2(d[1].x, d[1].y));
        u.h[3] = __float22bfloat162_rn(make_float2(d[1].z, d[1].w));
        *reinterpret_cast<bf16x8*>(&dst[r0 * 32 + p0 * 8]) = u.v;
        if (has2) {
            union { bf16x8 v; __hip_bfloat162 h[4]; } u2;
            u2.h[0] = __float22bfloat162_rn(make_float2(d[2].x, d[2].y));
            u2.h[1] = __float22bfloat162_rn(make_float2(d[2].z, d[2].w));
            u2.h[2] = __float22bfloat162_rn(make_float2(d[3].x, d[3].y));
            u2.h[3] = __float22bfloat162_rn(make_float2(d[3].z, d[3].w));
            *reinterpret_cast<bf16x8*>(&dst[r1 * 32 + p1 * 8]) = u2.v;
        }
    };

    const int q4  = kh * 2 + lh;
    const int spl = q4 ^ ((lj >> 1) & 3);

    auto compute = [&](int buf) {
        const unsigned short* Wb = WsBuf + buf * WSTEP;
        const unsigned short* Ab = AsBuf + buf * (ARR * 32);
        bf16x8 af[3];
        #pragma unroll
        for (int dt = 0; dt < 3; ++dt) {
            int r  = wu * 32 + lj + 2 - dt;
            int sl = q4 ^ ((r >> 1) & 3);
            af[dt] = *reinterpret_cast<const bf16x8*>(&Ab[r * 32 + sl * 8]);
        }
        #pragma unroll
        for (int dt = 0; dt < 3; ++dt) {
            const int nmf = (dt < 2) ? 5 : 3;
            #pragma unroll
            for (int mf = 0; mf < 5; ++mf) {
                if (mf < nmf) {
                    int j = dt * 160 + mf * 32 + lj;
                    bf16x8 bf = *reinterpret_cast<const bf16x8*>(&Wb[j * 32 + spl * 8]);
                    acc[mf] = __builtin_amdgcn_mfma_f32_32x32x16_bf16(
                        af[dt], bf, acc[mf], 0, 0, 0);
                }
            }
        }
    };

    // ---- prologue: stage step 0 (A loads + VALU W-gen) ----
    {
        float4 d[4];
        loadA(0, false, d);
        genW(WsBuf, 0);
        writeA(AsBuf, d);
        __syncthreads();
    }

    // ---- main loop: issue A(s+1) -> genW(s+1) VALU -> compute(s) -> writeA late ----
    for (int s = 0; s < NSTEP; ++s) {
        const int cur = s & 1, nxt = cur ^ 1;
        const bool dn = (s + 1 < NSTEP);
        float4 d[4];
        if (dn) {
            loadA((s + 1) * 32, (s + 1) == 12, d);    // issue early (covered by genW+MFMA)
            genW(WsBuf + nxt * WSTEP, s + 1);         // VALU, overlaps MFMA pipe
        }
        compute(cur);
        if (dn) writeA(AsBuf + nxt * (ARR * 32), d);  // write late
        __syncthreads();                              // vmcnt drain ~free (A consumed)
    }

    // ---- kh reduction via LDS + normalized stores ----
    float* xch = reinterpret_cast<float*>(smem);
    if (kh == 1) {
        #pragma unroll
        for (int mf = 0; mf < 5; ++mf) {
            int base = ((wu * 5 + mf) * 64 + lane) * 16;
            #pragma unroll
            for (int q = 0; q < 4; ++q)
                *reinterpret_cast<float4*>(&xch[base + q * 4]) =
                    make_float4(acc[mf][q * 4], acc[mf][q * 4 + 1],
                                acc[mf][q * 4 + 2], acc[mf][q * 4 + 3]);
        }
    }
    __syncthreads();
    if (kh == 0) {
        #pragma unroll
        for (int mf = 0; mf < 5; ++mf) {
            int base = ((wu * 5 + mf) * 64 + lane) * 16;
            float part[16];
            #pragma unroll
            for (int q = 0; q < 4; ++q) {
                float4 v = *reinterpret_cast<const float4*>(&xch[base + q * 4]);
                part[q * 4] = v.x; part[q * 4 + 1] = v.y;
                part[q * 4 + 2] = v.z; part[q * 4 + 3] = v.w;
            }
            int m = mf * 32 + lj;
            #pragma unroll
            for (int rg = 0; rg < 16; ++rg) {
                int u  = u0 + wu * 32 + (rg & 3) + 8 * (rg >> 2) + 4 * lh;
                int pe = u * HOP + m;
                int po = pe - (NFFT / 2);
                if (po >= 0 && po < OUTLEN)
                    out[(size_t)b * OUTLEN + po] = (acc[mf][rg] + part[rg]) * rssw[pe];
            }
        }
    }
}

// ---------------- launcher ----------------
extern "C" void kernel_launch(void* const* d_in, const int* in_sizes, int n_in,
                              void* d_out, int out_size, void* d_ws, size_t ws_size,
                              hipStream_t stream) {
    const float* x = (const float*)d_in[0];
    float* out = (float*)d_out;

    char* ws = (char*)d_ws;
    float* rssw  = (float*)ws;                       // ESTLEN floats = 1,920,960 B
    float* zpage = (float*)(ws + 1920960);           // 2048 B zeros

    hipMemsetAsync(zpage, 0, 2048, stream);
    build_rssw<<<(ESTLEN + 255) / 256, 256, 0, stream>>>(rssw);

    dim3 grid((T + UT - 1) / UT, BB);                // 32 x 16 = 512 = 2/CU
    istft_fused<<<grid, NTHR, 0, stream>>>(x, rssw, zpage, out);
}